// Round 2
// baseline (309.951 us; speedup 1.0000x reference)
//
#include <hip/hip_runtime.h>

// z_e: [B=64, D=64, H=64, W=64] fp32 ; embeddings: [K=512, D=64] fp32
// out: z_q_st [64,64,64,64] fp32 ++ loss (1 fp32)
constexpr int Dc  = 64;
constexpr int Kc  = 512;
constexpr int HWc = 4096;
constexpr int Nc  = 64 * HWc;                    // 262144 points
constexpr float INV_ELEMS = 1.0f / 16777216.0f;  // 1 / (B*D*H*W)

// ---- index-list macros (64 dims, grouped 16 per accumulator chain) --------
#define G0(M) M(0)M(1)M(2)M(3)M(4)M(5)M(6)M(7)M(8)M(9)M(10)M(11)M(12)M(13)M(14)M(15)
#define G1(M) M(16)M(17)M(18)M(19)M(20)M(21)M(22)M(23)M(24)M(25)M(26)M(27)M(28)M(29)M(30)M(31)
#define G2(M) M(32)M(33)M(34)M(35)M(36)M(37)M(38)M(39)M(40)M(41)M(42)M(43)M(44)M(45)M(46)M(47)
#define G3(M) M(48)M(49)M(50)M(51)M(52)M(53)M(54)M(55)M(56)M(57)M(58)M(59)M(60)M(61)M(62)M(63)
#define ALLD(M) G0(M) G1(M) G2(M) G3(M)

// ---- kernel 1: per-code squared norms ------------------------------------
__global__ __launch_bounds__(256) void vq_enorm(const float* __restrict__ emb,
                                                float* __restrict__ enorm2) {
    int k = blockIdx.x * blockDim.x + threadIdx.x;   // 0..511
    const float4* e = reinterpret_cast<const float4*>(emb + k * Dc);
    float s0 = 0.f, s1 = 0.f, s2 = 0.f, s3 = 0.f;
#pragma unroll
    for (int i = 0; i < Dc / 4; ++i) {
        float4 v = e[i];
        s0 = fmaf(v.x, v.x, s0);
        s1 = fmaf(v.y, v.y, s1);
        s2 = fmaf(v.z, v.z, s2);
        s3 = fmaf(v.w, v.w, s3);
    }
    enorm2[k] = (s0 + s1) + (s2 + s3);
}

// ---- kernel 2: main VQ ----------------------------------------------------
__global__ __launch_bounds__(256, 4) void vq_main(const float* __restrict__ z_e,
                                                  const float* __restrict__ emb,
                                                  const float* __restrict__ enorm2,
                                                  float* __restrict__ out,
                                                  float* __restrict__ acc) {
    const int p  = blockIdx.x * blockDim.x + threadIdx.x;  // point id
    const int b  = p >> 12;
    const int hw = p & 4095;

    const float* zp = z_e + (size_t)b * Dc * HWc + hw;

    // 64 NAMED registers for z — no indexable array the allocator can demote.
#define ZDECL(i) float z##i = zp[(size_t)(i) * HWc];
    ALLD(ZDECL)
#undef ZDECL

    // Pin all 64 in VGPRs: empty asm blocks rematerialization (zero cost).
    asm volatile("" : "+v"(z0),"+v"(z1),"+v"(z2),"+v"(z3),"+v"(z4),"+v"(z5),"+v"(z6),"+v"(z7));
    asm volatile("" : "+v"(z8),"+v"(z9),"+v"(z10),"+v"(z11),"+v"(z12),"+v"(z13),"+v"(z14),"+v"(z15));
    asm volatile("" : "+v"(z16),"+v"(z17),"+v"(z18),"+v"(z19),"+v"(z20),"+v"(z21),"+v"(z22),"+v"(z23));
    asm volatile("" : "+v"(z24),"+v"(z25),"+v"(z26),"+v"(z27),"+v"(z28),"+v"(z29),"+v"(z30),"+v"(z31));
    asm volatile("" : "+v"(z32),"+v"(z33),"+v"(z34),"+v"(z35),"+v"(z36),"+v"(z37),"+v"(z38),"+v"(z39));
    asm volatile("" : "+v"(z40),"+v"(z41),"+v"(z42),"+v"(z43),"+v"(z44),"+v"(z45),"+v"(z46),"+v"(z47));
    asm volatile("" : "+v"(z48),"+v"(z49),"+v"(z50),"+v"(z51),"+v"(z52),"+v"(z53),"+v"(z54),"+v"(z55));
    asm volatile("" : "+v"(z56),"+v"(z57),"+v"(z58),"+v"(z59),"+v"(z60),"+v"(z61),"+v"(z62),"+v"(z63));

    float best = 3.4e38f;
    int   bidx = 0;
    for (int k = 0; k < Kc; ++k) {
        const float* ek = emb + k * Dc;   // wave-uniform -> s_load, scalar pipe
        float s0 = 0.f, s1 = 0.f, s2 = 0.f, s3 = 0.f;
#define D0(i) s0 = fmaf(ek[i], z##i, s0);
#define D1(i) s1 = fmaf(ek[i], z##i, s1);
#define D2(i) s2 = fmaf(ek[i], z##i, s2);
#define D3(i) s3 = fmaf(ek[i], z##i, s3);
        G0(D0) G1(D1) G2(D2) G3(D3)
#undef D0
#undef D1
#undef D2
#undef D3
        float dot  = (s0 + s1) + (s2 + s3);
        float dist = fmaf(-2.0f, dot, enorm2[k]);   // ||z||^2 const: argmin-safe
        if (dist < best) { best = dist; bidx = k; } // strict <: first-occurrence
    }

    // epilogue: gather winning code, write z_q, accumulate squared error
    const float* embb = emb + bidx * Dc;           // divergent -> vector loads (L2-hot)
    float* op = out + (size_t)b * Dc * HWc + hw;
    float lsum = 0.f;
#define EPI(i) { float e = embb[i]; op[(size_t)(i) * HWc] = e; \
                 float f = e - z##i; lsum = fmaf(f, f, lsum); }
    ALLD(EPI)
#undef EPI

    // block reduction -> single atomic per block
    float v = lsum;
#pragma unroll
    for (int off = 32; off > 0; off >>= 1) v += __shfl_down(v, off);
    __shared__ float red[4];
    const int lane = threadIdx.x & 63;
    const int wid  = threadIdx.x >> 6;
    if (lane == 0) red[wid] = v;
    __syncthreads();
    if (threadIdx.x == 0) {
        float bs = (red[0] + red[1]) + (red[2] + red[3]);
        atomicAdd(acc, bs);
    }
}

// ---- kernel 3: finalize loss ----------------------------------------------
__global__ void vq_finalize(const float* __restrict__ acc, float* __restrict__ out_loss) {
    out_loss[0] = 1.25f * (acc[0] * INV_ELEMS);
}

extern "C" void kernel_launch(void* const* d_in, const int* in_sizes, int n_in,
                              void* d_out, int out_size, void* d_ws, size_t ws_size,
                              hipStream_t stream) {
    const float* z_e = (const float*)d_in[0];
    const float* emb = (const float*)d_in[1];
    float* out = (float*)d_out;

    float* acc    = (float*)d_ws;                 // 4 B accumulator
    float* enorm2 = (float*)((char*)d_ws + 256);  // 512 floats

    hipMemsetAsync(acc, 0, sizeof(float), stream);
    vq_enorm<<<Kc / 256, 256, 0, stream>>>(emb, enorm2);
    vq_main<<<Nc / 256, 256, 0, stream>>>(z_e, emb, enorm2, out, acc);
    vq_finalize<<<1, 1, 0, stream>>>(acc, out + (size_t)Nc * Dc);
}

// Round 3
// 309.825 us; speedup vs baseline: 1.0004x; 1.0004x over previous
//
#include <hip/hip_runtime.h>

// z_e: [B=64, D=64, H=64, W=64] fp32 ; embeddings: [K=512, D=64] fp32
// out: z_q_st [64,64,64,64] fp32 ++ loss (1 fp32)
constexpr int Dc  = 64;
constexpr int Kc  = 512;
constexpr int HWc = 4096;
constexpr int Nc  = 64 * HWc;                    // 262144 points
constexpr float INV_ELEMS = 1.0f / 16777216.0f;  // 1 / (B*D*H*W)

// ---- index-list macros (64 dims, grouped 16 per accumulator chain) --------
#define G0(M) M(0)M(1)M(2)M(3)M(4)M(5)M(6)M(7)M(8)M(9)M(10)M(11)M(12)M(13)M(14)M(15)
#define G1(M) M(16)M(17)M(18)M(19)M(20)M(21)M(22)M(23)M(24)M(25)M(26)M(27)M(28)M(29)M(30)M(31)
#define G2(M) M(32)M(33)M(34)M(35)M(36)M(37)M(38)M(39)M(40)M(41)M(42)M(43)M(44)M(45)M(46)M(47)
#define G3(M) M(48)M(49)M(50)M(51)M(52)M(53)M(54)M(55)M(56)M(57)M(58)M(59)M(60)M(61)M(62)M(63)
#define ALLD(M) G0(M) G1(M) G2(M) G3(M)

// ---- kernel 1: per-code squared norms ------------------------------------
__global__ __launch_bounds__(256) void vq_enorm(const float* __restrict__ emb,
                                                float* __restrict__ enorm2) {
    int k = blockIdx.x * blockDim.x + threadIdx.x;   // 0..511
    const float4* e = reinterpret_cast<const float4*>(emb + k * Dc);
    float s0 = 0.f, s1 = 0.f, s2 = 0.f, s3 = 0.f;
#pragma unroll
    for (int i = 0; i < Dc / 4; ++i) {
        float4 v = e[i];
        s0 = fmaf(v.x, v.x, s0);
        s1 = fmaf(v.y, v.y, s1);
        s2 = fmaf(v.z, v.z, s2);
        s3 = fmaf(v.w, v.w, s3);
    }
    enorm2[k] = (s0 + s1) + (s2 + s3);
}

// ---- kernel 2: main VQ ----------------------------------------------------
// waves_per_eu(4,4): clamp the backend's occupancy TARGET to 4 waves/SIMD so
// the register allocator gets the full 128-VGPR budget. launch_bounds alone
// only sets the minimum; the default heuristic spills to chase 8 waves.
__global__ __launch_bounds__(256)
__attribute__((amdgpu_waves_per_eu(4, 4)))
void vq_main(const float* __restrict__ z_e,
             const float* __restrict__ emb,
             const float* __restrict__ enorm2,
             float* __restrict__ out,
             float* __restrict__ acc) {
    const int p  = blockIdx.x * blockDim.x + threadIdx.x;  // point id
    const int b  = p >> 12;
    const int hw = p & 4095;

    const float* zp = z_e + (size_t)b * Dc * HWc + hw;

    // 64 NAMED registers for z — no indexable array the allocator can demote.
#define ZDECL(i) float z##i = zp[(size_t)(i) * HWc];
    ALLD(ZDECL)
#undef ZDECL

    // Pin in VGPRs (blocks rematerialization; zero-cost empty asm).
    asm volatile("" : "+v"(z0),"+v"(z1),"+v"(z2),"+v"(z3),"+v"(z4),"+v"(z5),"+v"(z6),"+v"(z7));
    asm volatile("" : "+v"(z8),"+v"(z9),"+v"(z10),"+v"(z11),"+v"(z12),"+v"(z13),"+v"(z14),"+v"(z15));
    asm volatile("" : "+v"(z16),"+v"(z17),"+v"(z18),"+v"(z19),"+v"(z20),"+v"(z21),"+v"(z22),"+v"(z23));
    asm volatile("" : "+v"(z24),"+v"(z25),"+v"(z26),"+v"(z27),"+v"(z28),"+v"(z29),"+v"(z30),"+v"(z31));
    asm volatile("" : "+v"(z32),"+v"(z33),"+v"(z34),"+v"(z35),"+v"(z36),"+v"(z37),"+v"(z38),"+v"(z39));
    asm volatile("" : "+v"(z40),"+v"(z41),"+v"(z42),"+v"(z43),"+v"(z44),"+v"(z45),"+v"(z46),"+v"(z47));
    asm volatile("" : "+v"(z48),"+v"(z49),"+v"(z50),"+v"(z51),"+v"(z52),"+v"(z53),"+v"(z54),"+v"(z55));
    asm volatile("" : "+v"(z56),"+v"(z57),"+v"(z58),"+v"(z59),"+v"(z60),"+v"(z61),"+v"(z62),"+v"(z63));

    float best = 3.4e38f;
    int   bidx = 0;
#pragma unroll 1
    for (int k = 0; k < Kc; ++k) {
        const float* ek = emb + k * Dc;   // wave-uniform -> s_load, scalar pipe
        float s0 = 0.f, s1 = 0.f, s2 = 0.f, s3 = 0.f;
#define D0(i) s0 = fmaf(ek[i], z##i, s0);
#define D1(i) s1 = fmaf(ek[i], z##i, s1);
#define D2(i) s2 = fmaf(ek[i], z##i, s2);
#define D3(i) s3 = fmaf(ek[i], z##i, s3);
        G0(D0) G1(D1) G2(D2) G3(D3)
#undef D0
#undef D1
#undef D2
#undef D3
        float dot  = (s0 + s1) + (s2 + s3);
        float dist = fmaf(-2.0f, dot, enorm2[k]);    // ||z||^2 const: argmin-safe
        bool  lt   = dist < best;                    // strict <: first-occurrence
        bidx = lt ? k : bidx;
        best = lt ? dist : best;
    }

    // epilogue: gather winning code, write z_q, accumulate squared error
    const float* embb = emb + bidx * Dc;             // divergent -> vector loads (L2-hot)
    float* op = out + (size_t)b * Dc * HWc + hw;
    float lsum = 0.f;
#define EPI(i) { float e = embb[i]; op[(size_t)(i) * HWc] = e; \
                 float f = e - z##i; lsum = fmaf(f, f, lsum); }
    ALLD(EPI)
#undef EPI

    // block reduction -> single atomic per block
    float v = lsum;
#pragma unroll
    for (int off = 32; off > 0; off >>= 1) v += __shfl_down(v, off);
    __shared__ float red[4];
    const int lane = threadIdx.x & 63;
    const int wid  = threadIdx.x >> 6;
    if (lane == 0) red[wid] = v;
    __syncthreads();
    if (threadIdx.x == 0) {
        float bs = (red[0] + red[1]) + (red[2] + red[3]);
        atomicAdd(acc, bs);
    }
}

// ---- kernel 3: finalize loss ----------------------------------------------
__global__ void vq_finalize(const float* __restrict__ acc, float* __restrict__ out_loss) {
    out_loss[0] = 1.25f * (acc[0] * INV_ELEMS);
}

extern "C" void kernel_launch(void* const* d_in, const int* in_sizes, int n_in,
                              void* d_out, int out_size, void* d_ws, size_t ws_size,
                              hipStream_t stream) {
    const float* z_e = (const float*)d_in[0];
    const float* emb = (const float*)d_in[1];
    float* out = (float*)d_out;

    float* acc    = (float*)d_ws;                 // 4 B accumulator
    float* enorm2 = (float*)((char*)d_ws + 256);  // 512 floats

    hipMemsetAsync(acc, 0, sizeof(float), stream);
    vq_enorm<<<Kc / 256, 256, 0, stream>>>(emb, enorm2);
    vq_main<<<Nc / 256, 256, 0, stream>>>(z_e, emb, enorm2, out, acc);
    vq_finalize<<<1, 1, 0, stream>>>(acc, out + (size_t)Nc * Dc);
}